// Round 1
// baseline (528.405 us; speedup 1.0000x reference)
//
#include <hip/hip_runtime.h>
#include <math.h>

#define BATCH 32
#define DIN   2048
#define DK    128
#define NREPS 400000
#define ACT   7
#define TN    128
#define NTILES (NREPS / TN)   /* 3125 */

__device__ __forceinline__ void topk_insert(float s, int n,
    float& d0, float& d1, float& d2, float& d3, float& d4,
    int& i0, int& i1, int& i2, int& i3, int& i4)
{
    if (s < d4) {
        if (s < d3) {
            d4 = d3; i4 = i3;
            if (s < d2) {
                d3 = d2; i3 = i2;
                if (s < d1) {
                    d2 = d1; i2 = i1;
                    if (s < d0) { d1 = d0; i1 = i0; d0 = s; i0 = n; }
                    else        { d1 = s;  i1 = n; }
                } else { d2 = s; i2 = n; }
            } else { d3 = s; i3 = n; }
        } else { d4 = s; i4 = n; }
    }
}

// ---------------------------------------------------------------------------
// Kernel 1: batch_rep = x @ W_enc + b_enc. Writes brep_t[k][b] = -2*br[b][k]
// (k-major, pre-scaled for the distance kernel) and brnorm[b] = ||br_b||^2.
// ---------------------------------------------------------------------------
__global__ __launch_bounds__(256) void encoder_kernel(
    const float* __restrict__ x, const float* __restrict__ W,
    const float* __restrict__ be, float* __restrict__ brept,
    float* __restrict__ brnorm)
{
    __shared__ float xs[DIN];
    __shared__ float part[256];
    __shared__ float vrow[DK];
    const int b = blockIdx.x, t = threadIdx.x;

    const float4* x4 = (const float4*)(x + (size_t)b * DIN);
    float4* xs4 = (float4*)xs;
    xs4[t]       = x4[t];
    xs4[t + 256] = x4[t + 256];
    __syncthreads();

    const int d = t & 127, h = t >> 7;
    const float* Wp = W + (size_t)(h * 1024) * DK + d;
    const float* xp = xs + h * 1024;
    float a0 = 0.f, a1 = 0.f, a2 = 0.f, a3 = 0.f;
    for (int i = 0; i < 1024; i += 4) {
        a0 = fmaf(xp[i],     Wp[(size_t)i * DK],       a0);
        a1 = fmaf(xp[i + 1], Wp[(size_t)(i + 1) * DK], a1);
        a2 = fmaf(xp[i + 2], Wp[(size_t)(i + 2) * DK], a2);
        a3 = fmaf(xp[i + 3], Wp[(size_t)(i + 3) * DK], a3);
    }
    part[t] = (a0 + a1) + (a2 + a3);
    __syncthreads();
    if (t < DK) {
        float v = part[t] + part[t + 128] + be[t];
        brept[t * BATCH + b] = -2.0f * v;
        vrow[t] = v * v;
    }
    __syncthreads();
    if (t == 0) {
        float s = 0.f;
        for (int i = 0; i < DK; i++) s += vrow[i];
        brnorm[b] = s;
    }
}

// ---------------------------------------------------------------------------
// Kernel 2: per-block partial top-5 per batch row over a grid-strided set of
// 128-row reps tiles. s = ||rep||^2 - 2*dot(br,rep) (||br||^2 added later).
// LDS: brt 16 KB (k-major, -2*br) + rpt 64 KB (k-major, XOR-swizzled cols).
// Thread (bg,ng) owns b=4bg..+3, n=4ng..+3; 4x4 accs + fused rep-norm.
// ---------------------------------------------------------------------------
__global__ __launch_bounds__(256) void dist_topk_kernel(
    const float* __restrict__ reps, const float* __restrict__ brept,
    float* __restrict__ pd, int* __restrict__ pi, int G)
{
    __shared__ float brt[DK * BATCH];   // 4096 f
    __shared__ float rpt[TN * DK];      // 16384 f (also merge scratch)

    const int t  = threadIdx.x, g = blockIdx.x;
    const int ng = t & 31, bg = t >> 5;

    { // stage brep_t (flat copy, coalesced, conflict-free)
        const float4* src = (const float4*)brept;
        float4* dst = (float4*)brt;
        #pragma unroll
        for (int i = 0; i < 4; i++) dst[t + 256 * i] = src[t + 256 * i];
    }

    float td0[4], td1[4], td2[4], td3[4], td4[4];
    int   ti0[4], ti1[4], ti2[4], ti3[4], ti4[4];
    #pragma unroll
    for (int i = 0; i < 4; i++) {
        td0[i] = td1[i] = td2[i] = td3[i] = td4[i] = 3.0e38f;
        ti0[i] = ti1[i] = ti2[i] = ti3[i] = ti4[i] = 0;
    }

    const int n_  = t >> 5;       // staging: row base, kq fixed per thread
    const int kq_ = t & 31;
    const int swz = (kq_ & 7) << 2;

    for (int tile = g; tile < NTILES; tile += G) {
        // ---- stage: coalesced flat float4 loads, swizzled transpose stores
        const float4* gsrc = (const float4*)(reps + (size_t)tile * (TN * DK));
        float4 v[16];
        #pragma unroll
        for (int i = 0; i < 16; i++) v[i] = gsrc[t + 256 * i];
        __syncthreads();            // previous tile's compute done
        #pragma unroll
        for (int i = 0; i < 16; i++) {
            const int n   = n_ + 8 * i;
            const int col = (((n & ~3) ^ swz) | (n & 3));
            const int base = (kq_ * 4) * DK + col;
            rpt[base]          = v[i].x;
            rpt[base + DK]     = v[i].y;
            rpt[base + 2 * DK] = v[i].z;
            rpt[base + 3 * DK] = v[i].w;
        }
        __syncthreads();

        // ---- compute 4x4 dots + rep norms
        float acc[4][4];
        float nrm[4];
        #pragma unroll
        for (int i = 0; i < 4; i++) {
            nrm[i] = 0.f;
            #pragma unroll
            for (int j = 0; j < 4; j++) acc[i][j] = 0.f;
        }
        const int colb = 4 * ng;
        #pragma unroll 2
        for (int kq = 0; kq < 32; kq++) {
            const int col   = colb ^ ((kq & 7) << 2);
            const int rbase = (kq * 4) * DK + col;
            const int bbase = (kq * 4) * BATCH + 4 * bg;
            #pragma unroll
            for (int j4 = 0; j4 < 4; j4++) {
                const float4 r  = *(const float4*)&rpt[rbase + j4 * DK];
                const float4 bb = *(const float4*)&brt[bbase + j4 * BATCH];
                acc[0][0] = fmaf(bb.x, r.x, acc[0][0]);
                acc[0][1] = fmaf(bb.x, r.y, acc[0][1]);
                acc[0][2] = fmaf(bb.x, r.z, acc[0][2]);
                acc[0][3] = fmaf(bb.x, r.w, acc[0][3]);
                acc[1][0] = fmaf(bb.y, r.x, acc[1][0]);
                acc[1][1] = fmaf(bb.y, r.y, acc[1][1]);
                acc[1][2] = fmaf(bb.y, r.z, acc[1][2]);
                acc[1][3] = fmaf(bb.y, r.w, acc[1][3]);
                acc[2][0] = fmaf(bb.z, r.x, acc[2][0]);
                acc[2][1] = fmaf(bb.z, r.y, acc[2][1]);
                acc[2][2] = fmaf(bb.z, r.z, acc[2][2]);
                acc[2][3] = fmaf(bb.z, r.w, acc[2][3]);
                acc[3][0] = fmaf(bb.w, r.x, acc[3][0]);
                acc[3][1] = fmaf(bb.w, r.y, acc[3][1]);
                acc[3][2] = fmaf(bb.w, r.z, acc[3][2]);
                acc[3][3] = fmaf(bb.w, r.w, acc[3][3]);
                nrm[0] = fmaf(r.x, r.x, nrm[0]);
                nrm[1] = fmaf(r.y, r.y, nrm[1]);
                nrm[2] = fmaf(r.z, r.z, nrm[2]);
                nrm[3] = fmaf(r.w, r.w, nrm[3]);
            }
        }

        // ---- top-k update
        const int nbase = tile * TN + 4 * ng;
        #pragma unroll
        for (int i = 0; i < 4; i++) {
            #pragma unroll
            for (int j = 0; j < 4; j++) {
                const float s = acc[i][j] + nrm[j];
                topk_insert(s, nbase + j,
                            td0[i], td1[i], td2[i], td3[i], td4[i],
                            ti0[i], ti1[i], ti2[i], ti3[i], ti4[i]);
            }
        }
    }

    // ---- block-level merge (reuse rpt as scratch)
    __syncthreads();
    float* candD = rpt;                       // 32*32*5 = 5120 f
    int*   candI = (int*)(rpt + 5120);        // 5120 i
    float* c2D   = rpt + 10240;               // 32*8*5 = 1280 f
    int*   c2I   = (int*)(rpt + 11520);       // 1280 i

    #pragma unroll
    for (int i = 0; i < 4; i++) {
        const int base = ((4 * bg + i) * 32 + ng) * 5;
        candD[base]     = td0[i]; candI[base]     = ti0[i];
        candD[base + 1] = td1[i]; candI[base + 1] = ti1[i];
        candD[base + 2] = td2[i]; candI[base + 2] = ti2[i];
        candD[base + 3] = td3[i]; candI[base + 3] = ti3[i];
        candD[base + 4] = td4[i]; candI[base + 4] = ti4[i];
    }
    __syncthreads();
    { // stage 2: 8 threads per b, each merges 4 ng-lists (20 entries)
        const int b = t >> 3, sub = t & 7;
        float d0 = 3.0e38f, d1 = 3.0e38f, d2 = 3.0e38f, d3 = 3.0e38f, d4 = 3.0e38f;
        int   i0 = 0, i1 = 0, i2 = 0, i3 = 0, i4 = 0;
        for (int q = 0; q < 4; q++) {
            const int base = (b * 32 + (sub * 4 + q)) * 5;
            #pragma unroll
            for (int e = 0; e < 5; e++)
                topk_insert(candD[base + e], candI[base + e],
                            d0, d1, d2, d3, d4, i0, i1, i2, i3, i4);
        }
        const int ob = (b * 8 + sub) * 5;
        c2D[ob] = d0; c2D[ob + 1] = d1; c2D[ob + 2] = d2; c2D[ob + 3] = d3; c2D[ob + 4] = d4;
        c2I[ob] = i0; c2I[ob + 1] = i1; c2I[ob + 2] = i2; c2I[ob + 3] = i3; c2I[ob + 4] = i4;
    }
    __syncthreads();
    if (t < 32) { // stage 3: final per-block top-5 for b=t
        const int b = t;
        float d0 = 3.0e38f, d1 = 3.0e38f, d2 = 3.0e38f, d3 = 3.0e38f, d4 = 3.0e38f;
        int   i0 = 0, i1 = 0, i2 = 0, i3 = 0, i4 = 0;
        for (int s2 = 0; s2 < 8; s2++) {
            const int base = (b * 8 + s2) * 5;
            #pragma unroll
            for (int e = 0; e < 5; e++)
                topk_insert(c2D[base + e], c2I[base + e],
                            d0, d1, d2, d3, d4, i0, i1, i2, i3, i4);
        }
        const int ob = (g * BATCH + b) * 5;
        pd[ob] = d0; pd[ob + 1] = d1; pd[ob + 2] = d2; pd[ob + 3] = d3; pd[ob + 4] = d4;
        pi[ob] = i0; pi[ob + 1] = i1; pi[ob + 2] = i2; pi[ob + 3] = i3; pi[ob + 4] = i4;
    }
}

// ---------------------------------------------------------------------------
// Kernel 3: merge G partial lists per b, softmax(-dist), gather actions.
// One block per batch row.
// ---------------------------------------------------------------------------
__global__ __launch_bounds__(256) void final_kernel(
    const float* __restrict__ pd, const int* __restrict__ pi,
    const float* __restrict__ brnorm, const float* __restrict__ actions,
    float* __restrict__ out, int G)
{
    __shared__ float lD[256 * 5];
    __shared__ int   lI[256 * 5];
    __shared__ float sD[32 * 5];
    __shared__ int   sI[32 * 5];
    const int b = blockIdx.x, t = threadIdx.x;

    float d0 = 3.0e38f, d1 = 3.0e38f, d2 = 3.0e38f, d3 = 3.0e38f, d4 = 3.0e38f;
    int   i0 = 0, i1 = 0, i2 = 0, i3 = 0, i4 = 0;
    for (int g = t; g < G; g += 256) {
        const int base = (g * BATCH + b) * 5;
        #pragma unroll
        for (int e = 0; e < 5; e++)
            topk_insert(pd[base + e], pi[base + e],
                        d0, d1, d2, d3, d4, i0, i1, i2, i3, i4);
    }
    lD[t * 5] = d0; lD[t * 5 + 1] = d1; lD[t * 5 + 2] = d2; lD[t * 5 + 3] = d3; lD[t * 5 + 4] = d4;
    lI[t * 5] = i0; lI[t * 5 + 1] = i1; lI[t * 5 + 2] = i2; lI[t * 5 + 3] = i3; lI[t * 5 + 4] = i4;
    __syncthreads();
    if (t < 32) {
        d0 = d1 = d2 = d3 = d4 = 3.0e38f; i0 = i1 = i2 = i3 = i4 = 0;
        for (int s = 0; s < 8; s++) {
            const int base = (t * 8 + s) * 5;
            #pragma unroll
            for (int e = 0; e < 5; e++)
                topk_insert(lD[base + e], lI[base + e],
                            d0, d1, d2, d3, d4, i0, i1, i2, i3, i4);
        }
        sD[t * 5] = d0; sD[t * 5 + 1] = d1; sD[t * 5 + 2] = d2; sD[t * 5 + 3] = d3; sD[t * 5 + 4] = d4;
        sI[t * 5] = i0; sI[t * 5 + 1] = i1; sI[t * 5 + 2] = i2; sI[t * 5 + 3] = i3; sI[t * 5 + 4] = i4;
    }
    __syncthreads();
    if (t == 0) {
        d0 = d1 = d2 = d3 = d4 = 3.0e38f; i0 = i1 = i2 = i3 = i4 = 0;
        for (int s = 0; s < 32; s++) {
            const int base = s * 5;
            #pragma unroll
            for (int e = 0; e < 5; e++)
                topk_insert(sD[base + e], sI[base + e],
                            d0, d1, d2, d3, d4, i0, i1, i2, i3, i4);
        }
        const float bn = brnorm[b];
        float dist[5]; int idx[5];
        dist[0] = d0; dist[1] = d1; dist[2] = d2; dist[3] = d3; dist[4] = d4;
        idx[0] = i0; idx[1] = i1; idx[2] = i2; idx[3] = i3; idx[4] = i4;
        float dmin = 3.0e38f;
        #pragma unroll
        for (int e = 0; e < 5; e++) {
            dist[e] = sqrtf(fmaxf(dist[e] + bn, 1e-12f));
            dmin = fminf(dmin, dist[e]);
        }
        float w[5], wsum = 0.f;
        #pragma unroll
        for (int e = 0; e < 5; e++) { w[e] = expf(dmin - dist[e]); wsum += w[e]; }
        const float inv = 1.0f / wsum;
        for (int a = 0; a < ACT; a++) {
            float o = 0.f;
            #pragma unroll
            for (int e = 0; e < 5; e++)
                o = fmaf(w[e], actions[(size_t)idx[e] * ACT + a], o);
            out[b * ACT + a] = o * inv;
        }
    }
}

extern "C" void kernel_launch(void* const* d_in, const int* in_sizes, int n_in,
                              void* d_out, int out_size, void* d_ws, size_t ws_size,
                              hipStream_t stream)
{
    (void)in_sizes; (void)n_in; (void)out_size;
    const float* x       = (const float*)d_in[0];
    const float* W       = (const float*)d_in[1];
    const float* be      = (const float*)d_in[2];
    const float* reps    = (const float*)d_in[3];
    const float* actions = (const float*)d_in[4];
    // d_in[5] = k (always 5; top-5 is structural in the kernels)

    float* ws     = (float*)d_ws;
    float* brept  = ws;            // 4096 floats  (brep_t[k][b], pre-scaled -2)
    float* brnorm = ws + 4096;     // 32 floats
    float* pd     = ws + 4224;     // G*32*5 floats

    int G = 512;                   // 2 blocks/CU at 80 KB LDS, all-resident
    {
        const size_t avail_f = ws_size / 4;
        if (avail_f < 4224 + (size_t)G * 320) {
            long fit = ((long)avail_f - 4224) / 320;
            G = (fit < 1) ? 1 : (int)fit;
            if (G > 512) G = 512;
        }
    }
    int* pi = (int*)(pd + (size_t)G * BATCH * 5);

    encoder_kernel  <<<32, 256, 0, stream>>>(x, W, be, brept, brnorm);
    dist_topk_kernel<<<G,  256, 0, stream>>>(reps, brept, pd, pi, G);
    final_kernel    <<<32, 256, 0, stream>>>(pd, pi, brnorm, actions, out_size ? (float*)d_out : (float*)d_out, G);
}

// Round 2
// 494.954 us; speedup vs baseline: 1.0676x; 1.0676x over previous
//
#include <hip/hip_runtime.h>
#include <math.h>

#define BATCH 32
#define DIN   2048
#define DK    128
#define NREPS 400000
#define ACT   7
#define NGRP  (NREPS / 64)   /* 6250 groups of 64 rows, exact */

__device__ __forceinline__ void topk_insert(float s, int n,
    float& d0, float& d1, float& d2, float& d3, float& d4,
    int& i0, int& i1, int& i2, int& i3, int& i4)
{
    if (s < d4) {
        if (s < d3) {
            d4 = d3; i4 = i3;
            if (s < d2) {
                d3 = d2; i3 = i2;
                if (s < d1) {
                    d2 = d1; i2 = i1;
                    if (s < d0) { d1 = d0; i1 = i0; d0 = s; i0 = n; }
                    else        { d1 = s;  i1 = n; }
                } else { d2 = s; i2 = n; }
            } else { d3 = s; i3 = n; }
        } else { d4 = s; i4 = n; }
    }
}

// ---------------------------------------------------------------------------
// Kernel 1: batch_rep = x @ W_enc + b_enc. Writes brep_t[k][b] = -2*br[b][k]
// (k-major, pre-scaled) and brnorm[b] = ||br_b||^2.
// ---------------------------------------------------------------------------
__global__ __launch_bounds__(256) void encoder_kernel(
    const float* __restrict__ x, const float* __restrict__ W,
    const float* __restrict__ be, float* __restrict__ brept,
    float* __restrict__ brnorm)
{
    __shared__ float xs[DIN];
    __shared__ float part[256];
    __shared__ float vrow[DK];
    const int b = blockIdx.x, t = threadIdx.x;

    const float4* x4 = (const float4*)(x + (size_t)b * DIN);
    float4* xs4 = (float4*)xs;
    xs4[t]       = x4[t];
    xs4[t + 256] = x4[t + 256];
    __syncthreads();

    const int d = t & 127, h = t >> 7;
    const float* Wp = W + (size_t)(h * 1024) * DK + d;
    const float* xp = xs + h * 1024;
    float a0 = 0.f, a1 = 0.f, a2 = 0.f, a3 = 0.f;
    for (int i = 0; i < 1024; i += 4) {
        a0 = fmaf(xp[i],     Wp[(size_t)i * DK],       a0);
        a1 = fmaf(xp[i + 1], Wp[(size_t)(i + 1) * DK], a1);
        a2 = fmaf(xp[i + 2], Wp[(size_t)(i + 2) * DK], a2);
        a3 = fmaf(xp[i + 3], Wp[(size_t)(i + 3) * DK], a3);
    }
    part[t] = (a0 + a1) + (a2 + a3);
    __syncthreads();
    if (t < DK) {
        float v = part[t] + part[t + 128] + be[t];
        brept[t * BATCH + b] = -2.0f * v;
        vrow[t] = v * v;
    }
    __syncthreads();
    if (t == 0) {
        float s = 0.f;
        for (int i = 0; i < DK; i++) s += vrow[i];
        brnorm[b] = s;
    }
}

// ---------------------------------------------------------------------------
// Kernel 2: lane-per-row streaming distance + per-wave top-5.
// Each lane owns one rep row per group: streams 128 floats as 8xfloat4 per
// 32-k superchunk (full cache lines, fetched once), holds acc[32] (one per
// batch row). br operand is wave-uniform -> scalar/L1-cached loads.
// Per-wave LDS round-trip (stride 36, conflict-free) redistributes dists to
// (b, half)-owning lanes for register top-5. No __syncthreads in hot loop.
// ---------------------------------------------------------------------------
__global__ __launch_bounds__(256, 4) void dist_topk_kernel(
    const float* __restrict__ reps, const float* __restrict__ brt,
    float* __restrict__ pd, int* __restrict__ pi, int nwaves)
{
    __shared__ float wdist[4 * 64 * 36];   // 36 KB, per-wave slabs
    const int t = threadIdx.x, g = blockIdx.x;
    const int wid = t >> 6, ln = t & 63;
    const int b = ln & 31, h = ln >> 5;
    float* wd = wdist + wid * (64 * 36);

    float d0 = 3.0e38f, d1 = 3.0e38f, d2 = 3.0e38f, d3 = 3.0e38f, d4 = 3.0e38f;
    int   i0 = 0, i1 = 0, i2 = 0, i3 = 0, i4 = 0;

    for (int grp = g * 4 + wid; grp < NGRP; grp += nwaves) {
        const float4* rp = (const float4*)(reps + (size_t)(grp * 64 + ln) * DK);
        float acc[32];
        #pragma unroll
        for (int i = 0; i < 32; i++) acc[i] = 0.f;
        float nrm = 0.f;

        #pragma unroll 1
        for (int c = 0; c < 4; c++) {          // 4 superchunks of 32 k
            float4 r[8];
            #pragma unroll
            for (int q = 0; q < 8; q++) r[q] = rp[c * 8 + q];
            const float* bp0 = brt + c * 32 * BATCH;
            #pragma unroll
            for (int q = 0; q < 8; q++) {
                const float4 rr = r[q];
                nrm = fmaf(rr.x, rr.x, nrm);
                nrm = fmaf(rr.y, rr.y, nrm);
                nrm = fmaf(rr.z, rr.z, nrm);
                nrm = fmaf(rr.w, rr.w, nrm);
                const float* bp = bp0 + q * 4 * BATCH;
                #pragma unroll
                for (int bb = 0; bb < 32; bb++) {
                    float a = acc[bb];
                    a = fmaf(bp[bb],             rr.x, a);
                    a = fmaf(bp[BATCH + bb],     rr.y, a);
                    a = fmaf(bp[2 * BATCH + bb], rr.z, a);
                    a = fmaf(bp[3 * BATCH + bb], rr.w, a);
                    acc[bb] = a;
                }
            }
        }

        // scatter this lane's 32 dists (one per batch row) to the wave slab
        #pragma unroll
        for (int q = 0; q < 8; q++) {
            float4 v;
            v.x = acc[4 * q]     + nrm;
            v.y = acc[4 * q + 1] + nrm;
            v.z = acc[4 * q + 2] + nrm;
            v.w = acc[4 * q + 3] + nrm;
            *(float4*)&wd[ln * 36 + 4 * q] = v;
        }
        asm volatile("s_waitcnt lgkmcnt(0)" ::: "memory");

        // lane (b,h) scans 32 rows of its half, inserts into register top-5
        const int nb = grp * 64;
        #pragma unroll 4
        for (int s = 0; s < 32; s++) {
            const int row = h * 32 + s;
            const float dv = wd[row * 36 + b];
            topk_insert(dv, nb + row, d0, d1, d2, d3, d4, i0, i1, i2, i3, i4);
        }
        asm volatile("s_waitcnt lgkmcnt(0)" ::: "memory");
    }

    // ---- block merge: 8 lists (4 waves x 2 halves) per batch row
    __syncthreads();
    float* cD = wdist;                 // 256*5 = 1280 f
    int*   cI = (int*)(wdist + 1280);  // 1280 i
    {
        const int base = t * 5;
        cD[base]     = d0; cI[base]     = i0;
        cD[base + 1] = d1; cI[base + 1] = i1;
        cD[base + 2] = d2; cI[base + 2] = i2;
        cD[base + 3] = d3; cI[base + 3] = i3;
        cD[base + 4] = d4; cI[base + 4] = i4;
    }
    __syncthreads();
    if (t < 32) {
        float e0 = 3.0e38f, e1 = 3.0e38f, e2 = 3.0e38f, e3 = 3.0e38f, e4 = 3.0e38f;
        int   j0 = 0, j1 = 0, j2 = 0, j3 = 0, j4 = 0;
        for (int j = 0; j < 8; j++) {
            const int base = (t + 32 * j) * 5;
            #pragma unroll
            for (int e = 0; e < 5; e++)
                topk_insert(cD[base + e], cI[base + e],
                            e0, e1, e2, e3, e4, j0, j1, j2, j3, j4);
        }
        const int ob = (g * BATCH + t) * 5;
        pd[ob] = e0; pd[ob + 1] = e1; pd[ob + 2] = e2; pd[ob + 3] = e3; pd[ob + 4] = e4;
        pi[ob] = j0; pi[ob + 1] = j1; pi[ob + 2] = j2; pi[ob + 3] = j3; pi[ob + 4] = j4;
    }
}

// ---------------------------------------------------------------------------
// Kernel 3: merge G partial lists per b, softmax(-dist), gather actions.
// ---------------------------------------------------------------------------
__global__ __launch_bounds__(256) void final_kernel(
    const float* __restrict__ pd, const int* __restrict__ pi,
    const float* __restrict__ brnorm, const float* __restrict__ actions,
    float* __restrict__ out, int G)
{
    __shared__ float lD[256 * 5];
    __shared__ int   lI[256 * 5];
    __shared__ float sD[32 * 5];
    __shared__ int   sI[32 * 5];
    const int b = blockIdx.x, t = threadIdx.x;

    float d0 = 3.0e38f, d1 = 3.0e38f, d2 = 3.0e38f, d3 = 3.0e38f, d4 = 3.0e38f;
    int   i0 = 0, i1 = 0, i2 = 0, i3 = 0, i4 = 0;
    for (int g = t; g < G; g += 256) {
        const int base = (g * BATCH + b) * 5;
        #pragma unroll
        for (int e = 0; e < 5; e++)
            topk_insert(pd[base + e], pi[base + e],
                        d0, d1, d2, d3, d4, i0, i1, i2, i3, i4);
    }
    lD[t * 5] = d0; lD[t * 5 + 1] = d1; lD[t * 5 + 2] = d2; lD[t * 5 + 3] = d3; lD[t * 5 + 4] = d4;
    lI[t * 5] = i0; lI[t * 5 + 1] = i1; lI[t * 5 + 2] = i2; lI[t * 5 + 3] = i3; lI[t * 5 + 4] = i4;
    __syncthreads();
    if (t < 32) {
        d0 = d1 = d2 = d3 = d4 = 3.0e38f; i0 = i1 = i2 = i3 = i4 = 0;
        for (int s = 0; s < 8; s++) {
            const int base = (t * 8 + s) * 5;
            #pragma unroll
            for (int e = 0; e < 5; e++)
                topk_insert(lD[base + e], lI[base + e],
                            d0, d1, d2, d3, d4, i0, i1, i2, i3, i4);
        }
        sD[t * 5] = d0; sD[t * 5 + 1] = d1; sD[t * 5 + 2] = d2; sD[t * 5 + 3] = d3; sD[t * 5 + 4] = d4;
        sI[t * 5] = i0; sI[t * 5 + 1] = i1; sI[t * 5 + 2] = i2; sI[t * 5 + 3] = i3; sI[t * 5 + 4] = i4;
    }
    __syncthreads();
    if (t == 0) {
        d0 = d1 = d2 = d3 = d4 = 3.0e38f; i0 = i1 = i2 = i3 = i4 = 0;
        for (int s = 0; s < 32; s++) {
            const int base = s * 5;
            #pragma unroll
            for (int e = 0; e < 5; e++)
                topk_insert(sD[base + e], sI[base + e],
                            d0, d1, d2, d3, d4, i0, i1, i2, i3, i4);
        }
        const float bn = brnorm[b];
        float dist[5]; int idx[5];
        dist[0] = d0; dist[1] = d1; dist[2] = d2; dist[3] = d3; dist[4] = d4;
        idx[0] = i0; idx[1] = i1; idx[2] = i2; idx[3] = i3; idx[4] = i4;
        float dmin = 3.0e38f;
        #pragma unroll
        for (int e = 0; e < 5; e++) {
            dist[e] = sqrtf(fmaxf(dist[e] + bn, 1e-12f));
            dmin = fminf(dmin, dist[e]);
        }
        float w[5], wsum = 0.f;
        #pragma unroll
        for (int e = 0; e < 5; e++) { w[e] = expf(dmin - dist[e]); wsum += w[e]; }
        const float inv = 1.0f / wsum;
        for (int a = 0; a < ACT; a++) {
            float o = 0.f;
            #pragma unroll
            for (int e = 0; e < 5; e++)
                o = fmaf(w[e], actions[(size_t)idx[e] * ACT + a], o);
            out[b * ACT + a] = o * inv;
        }
    }
}

extern "C" void kernel_launch(void* const* d_in, const int* in_sizes, int n_in,
                              void* d_out, int out_size, void* d_ws, size_t ws_size,
                              hipStream_t stream)
{
    (void)in_sizes; (void)n_in; (void)out_size;
    const float* x       = (const float*)d_in[0];
    const float* W       = (const float*)d_in[1];
    const float* be      = (const float*)d_in[2];
    const float* reps    = (const float*)d_in[3];
    const float* actions = (const float*)d_in[4];
    // d_in[5] = k (always 5; structural)

    float* ws     = (float*)d_ws;
    float* brept  = ws;            // 4096 floats (brep_t[k][b], pre-scaled -2)
    float* brnorm = ws + 4096;     // 32 floats
    float* pd     = ws + 4224;     // G*32*5 floats

    int G = 782;                   // 3128 waves -> 6250 groups = ~2 each, balanced
    {
        const size_t avail_f = ws_size / 4;
        if (avail_f < 4224 + (size_t)G * 320) {
            long fit = ((long)avail_f - 4224) / 320;
            G = (fit < 1) ? 1 : (int)fit;
            if (G > 782) G = 782;
        }
    }
    int* pi = (int*)(pd + (size_t)G * BATCH * 5);
    const int nwaves = G * 4;

    encoder_kernel  <<<32, 256, 0, stream>>>(x, W, be, brept, brnorm);
    dist_topk_kernel<<<G,  256, 0, stream>>>(reps, brept, pd, pi, nwaves);
    final_kernel    <<<32, 256, 0, stream>>>(pd, pi, brnorm, actions, (float*)d_out, G);
}